// Round 7
// baseline (316.618 us; speedup 1.0000x reference)
//
#include <hip/hip_runtime.h>
#include <hip/hip_bf16.h>
#include <math.h>

#define H_ 16
#define DK_ 128
#define DV_ 128
#define D_ 2048
#define T_ 256
#define B_ 2
#define BT_ 512

typedef __attribute__((ext_vector_type(8))) short short8v;
typedef __attribute__((ext_vector_type(4))) float float4v;
typedef unsigned short ushort_t;

__device__ __forceinline__ float sigmoidf_(float x){ return 1.f/(1.f+expf(-x)); }
__device__ __forceinline__ float siluf_(float x){ return x/(1.f+expf(-x)); }
__device__ __forceinline__ ushort_t f2bf(float f){
    __hip_bfloat16 h = __float2bfloat16(f);
    return *reinterpret_cast<ushort_t*>(&h);
}
// swizzled LDS index (shorts) for 64-row x 32-col bf16 tiles; k multiple of 8 in use
__device__ __forceinline__ int swz(int row, int k){
    return row * 32 + ((((k >> 3) ^ (row & 3)) << 3) | (k & 7));
}

// ---------------- fp32 -> bf16 elementwise ----------------
__global__ void cvt_bf16(const float* __restrict__ in, ushort_t* __restrict__ out, int n){
    int i = (blockIdx.x * 256 + threadIdx.x) * 4;
    if (i >= n) return;
    float4 v = *(const float4*)&in[i];
    union { ushort_t s[4]; unsigned long long u; } p;
    p.s[0] = f2bf(v.x); p.s[1] = f2bf(v.y); p.s[2] = f2bf(v.z); p.s[3] = f2bf(v.w);
    *(unsigned long long*)&out[i] = p.u;
}

// ---------------- strided cvt: C_big cols [6208,6336) -> gtmpb [512][128] bf16 ------
__global__ void cvt_strided(const float* __restrict__ Cb, ushort_t* __restrict__ out){
    int i = (blockIdx.x * 256 + threadIdx.x) * 4;   // 65536 total
    int m = i >> 7, c = i & 127;
    float4 v = *(const float4*)&Cb[(size_t)m * 6336 + 6208 + c];
    union { ushort_t s[4]; unsigned long long u; } p;
    p.s[0] = f2bf(v.x); p.s[1] = f2bf(v.y); p.s[2] = f2bf(v.z); p.s[3] = f2bf(v.w);
    *(unsigned long long*)&out[i] = p.u;
}

// ---------------- GEMM core: C[64x64 tile] = A_bf16[M,K] @ W_f32[K,Nst] -------------
// W transpose-converted inline into swizzled LDS; register ping-pong prefetch.
__device__ __forceinline__ void gemm_core(
    const ushort_t* __restrict__ A, int K,
    const float* __restrict__ W, int Nst, int nloc0,
    float* __restrict__ C, int Cst, int m0, int n0out)
{
    __shared__ ushort_t Asub[2048];
    __shared__ ushort_t Bsub[2048];
    const int tid = threadIdx.x;
    const int wid = tid >> 6, lane = tid & 63;
    const int wr = (wid >> 1) * 32, wc = (wid & 1) * 32;
    const int lr = lane & 15, lk = (lane >> 4) * 8;
    const int rowA = tid >> 2, kqA = tid & 3;       // A staging: b128 per thread
    const int nW = tid & 63, kqW = tid >> 6;        // W staging: 8 scalar rows

    float4v acc[2][2];
    #pragma unroll
    for (int i = 0; i < 2; ++i)
        #pragma unroll
        for (int j = 0; j < 2; ++j) acc[i][j] = (float4v){0.f, 0.f, 0.f, 0.f};

    short8v aRa, aRb;
    float wRa[8], wRb[8];

#define LOADT(AR, WR, KOFF) do {                                                   \
    AR = *(const short8v*)&A[(size_t)(m0 + rowA) * K + (KOFF) + kqA * 8];          \
    _Pragma("unroll")                                                              \
    for (int r = 0; r < 8; ++r)                                                    \
        WR[r] = W[(size_t)((KOFF) + kqW * 8 + r) * Nst + nloc0 + nW];              \
} while (0)
#define STORET(AR, WR) do {                                                        \
    *(short8v*)&Asub[swz(rowA, kqA * 8)] = AR;                                     \
    union { ushort_t s[8]; short8v v; } pk;                                        \
    _Pragma("unroll")                                                              \
    for (int r = 0; r < 8; ++r) pk.s[r] = f2bf(WR[r]);                             \
    *(short8v*)&Bsub[swz(nW, kqW * 8)] = pk.v;                                     \
} while (0)
#define FRAGMMA() do {                                                             \
    short8v af0 = *(const short8v*)&Asub[swz(wr + lr, lk)];                        \
    short8v af1 = *(const short8v*)&Asub[swz(wr + 16 + lr, lk)];                   \
    short8v bf0 = *(const short8v*)&Bsub[swz(wc + lr, lk)];                        \
    short8v bf1 = *(const short8v*)&Bsub[swz(wc + 16 + lr, lk)];                   \
    acc[0][0] = __builtin_amdgcn_mfma_f32_16x16x32_bf16(af0, bf0, acc[0][0],0,0,0);\
    acc[0][1] = __builtin_amdgcn_mfma_f32_16x16x32_bf16(af0, bf1, acc[0][1],0,0,0);\
    acc[1][0] = __builtin_amdgcn_mfma_f32_16x16x32_bf16(af1, bf0, acc[1][0],0,0,0);\
    acc[1][1] = __builtin_amdgcn_mfma_f32_16x16x32_bf16(af1, bf1, acc[1][1],0,0,0);\
} while (0)

    LOADT(aRa, wRa, 0);
    for (int k0 = 0; k0 < K; k0 += 64) {
        STORET(aRa, wRa);
        __syncthreads();
        if (k0 + 32 < K) LOADT(aRb, wRb, k0 + 32);
        FRAGMMA();
        __syncthreads();
        STORET(aRb, wRb);
        __syncthreads();
        if (k0 + 64 < K) LOADT(aRa, wRa, k0 + 64);
        FRAGMMA();
        __syncthreads();
    }
#undef LOADT
#undef STORET
#undef FRAGMMA
    const int lq = (lane >> 4) * 4;
    #pragma unroll
    for (int mi = 0; mi < 2; ++mi)
        #pragma unroll
        for (int ni = 0; ni < 2; ++ni)
            #pragma unroll
            for (int j = 0; j < 4; ++j)
                C[(size_t)(m0 + wr + mi * 16 + lq + j) * Cst + (n0out + wc + ni * 16 + lr)]
                    = acc[mi][ni][j];
}

// fused projection GEMM: N = 6336 = wq(2048) | wk(2048) | wv(2048) | unc(64) | g1(128)
__global__ __launch_bounds__(256) void gemm_proj(const ushort_t* __restrict__ A,
    const float* __restrict__ wq, const float* __restrict__ wk, const float* __restrict__ wv,
    const float* __restrict__ unc, const float* __restrict__ g1, float* __restrict__ C)
{
    int n0 = blockIdx.x * 64, m0 = blockIdx.y * 64;
    const float* W; int nloc, Nst;
    if (n0 < 2048)      { W = wq;  nloc = n0;        Nst = 2048; }
    else if (n0 < 4096) { W = wk;  nloc = n0 - 2048; Nst = 2048; }
    else if (n0 < 6144) { W = wv;  nloc = n0 - 4096; Nst = 2048; }
    else if (n0 < 6208) { W = unc; nloc = n0 - 6144; Nst = 64; }
    else                { W = g1;  nloc = n0 - 6208; Nst = 128; }
    gemm_core(A, 2048, W, Nst, nloc, C, 6336, m0, n0);
}

// single-weight GEMM: C[M,N] = A[M,K] @ W[K,N]
__global__ __launch_bounds__(256) void gemm_one(const ushort_t* __restrict__ A,
    const float* __restrict__ W, float* __restrict__ C, int N, int K)
{
    gemm_core(A, K, W, N, blockIdx.x * 64, C, N, blockIdx.y * 64, blockIdx.x * 64);
}

// ---------------- fused causal depthwise conv (K=4) + SiLU over q|k|v --------------
// also emits bf16 copy of k-section (for the vhat GEMM)
__global__ void conv_fused(const float* __restrict__ Cb,
    const float* __restrict__ wq, const float* __restrict__ wk, const float* __restrict__ wv,
    float* __restrict__ qc, float* __restrict__ kc, float* __restrict__ vc,
    ushort_t* __restrict__ kcb, float qscale)
{
    int c  = blockIdx.x * 256 + threadIdx.x;   // 0..6143
    int bt = blockIdx.y;
    int b  = bt / T_, t = bt % T_;
    int which = c >> 11, cloc = c & 2047;
    const float* w = which == 0 ? wq : which == 1 ? wk : wv;
    float* o = which == 0 ? qc : which == 1 ? kc : vc;
    float scale = which == 0 ? qscale : 1.f;
    float acc = 0.f;
    #pragma unroll
    for (int j = 0; j < 4; ++j) {
        int tt = t - 3 + j;
        if (tt >= 0) acc = fmaf(w[cloc * 4 + j], Cb[((size_t)(b * T_ + tt)) * 6336 + c], acc);
    }
    float r = siluf_(acc) * scale;
    o[(size_t)bt * D_ + cloc] = r;
    if (which == 1) kcb[(size_t)bt * D_ + cloc] = f2bf(r);
}

// ---------------- g_chan (pre-scaled by log2(e) for exp2f) ----------------
__global__ void gchan_k(const float* __restrict__ A_log, const float* __restrict__ dt_bias,
                        float* __restrict__ gchan)
{
    int i = blockIdx.x * 256 + threadIdx.x;
    int h = i >> 7;
    float x = dt_bias[i];
    float sp = (x > 20.f) ? x : log1pf(expf(x));
    gchan[i] = -expf(A_log[h]) * sp * 1.44269504088896f;
}

// ---------------- per-(b,t,h) features (+inline entropy) + tiny MLP ----------------
__global__ __launch_bounds__(128) void feats_k(
    const float* __restrict__ kc, const float* __restrict__ vc,
    const float* __restrict__ vhatA, const float* __restrict__ Cb,
    const float* __restrict__ he,
    const float* __restrict__ w1, const float* __restrict__ b1,
    const float* __restrict__ w2, const float* __restrict__ b2,
    const float* __restrict__ bbw, const float* __restrict__ bbb,
    const float* __restrict__ bdw, const float* __restrict__ bdb,
    const float* __restrict__ lamw, const float* __restrict__ lamb,
    const float* __restrict__ abw, const float* __restrict__ abb,
    const float* __restrict__ adw, const float* __restrict__ adb,
    float* __restrict__ bf, float* __restrict__ bs, float* __restrict__ lm,
    float* __restrict__ af, float* __restrict__ as2, float* __restrict__ kn)
{
    int blk = blockIdx.x;          // (b*T+t)*H + h
    int h = blk & 15, bt = blk >> 4;
    int b = bt / T_, t = bt % T_;
    int v = threadIdx.x;           // 0..127
    __shared__ float part[2][5];
    __shared__ float tot5[5];
    __shared__ float feats8[8];
    __shared__ float hf1[32];
    __shared__ float hf[32];
    __shared__ float entSh;

    // entropy of softmax over 64 logits (wave 0)
    if (v < 64) {
        float x = Cb[(size_t)bt * 6336 + 6144 + v];
        float m = x;
        #pragma unroll
        for (int o = 32; o > 0; o >>= 1) m = fmaxf(m, __shfl_xor(m, o));
        float e = expf(x - m);
        float s = e;
        #pragma unroll
        for (int o = 32; o > 0; o >>= 1) s += __shfl_xor(s, o);
        float lp = (x - m) - logf(s);
        float c = -expf(lp) * lp;
        #pragma unroll
        for (int o = 32; o > 0; o >>= 1) c += __shfl_xor(c, o);
        if (v == 0) entSh = c / logf(64.f);
    }

    size_t base = (size_t)bt * D_ + h * 128;
    float kval = kc[base + v];
    float vval = vc[base + v];
    float vhat = vhatA[(size_t)blk * 128 + v];

    float e = vval - vhat;
    float sums[5] = {kval * kval, vval * vval, vhat * vhat, vval * vhat, e * e};
    #pragma unroll
    for (int i = 0; i < 5; ++i) {
        float s = sums[i];
        #pragma unroll
        for (int o = 32; o > 0; o >>= 1) s += __shfl_xor(s, o);
        if ((threadIdx.x & 63) == 0) part[threadIdx.x >> 6][i] = s;
    }
    __syncthreads();
    if (threadIdx.x < 5) tot5[threadIdx.x] = part[0][threadIdx.x] + part[1][threadIdx.x];
    __syncthreads();
    if (threadIdx.x == 0) {
        float k2 = tot5[0], v2 = tot5[1], vh2 = tot5[2], vvh = tot5[3], e2 = tot5[4];
        float knorm = sqrtf(k2);
        float err_n = sqrtf(e2);
        float v_n = sqrtf(v2);
        float vh_n = sqrtf(vh2);
        feats8[0] = entSh;
        feats8[1] = err_n / (v_n + 1e-6f);
        feats8[2] = vvh / (v_n * vh_n + 1e-6f);
        feats8[3] = log1pf(err_n);
        feats8[4] = he[h * 4 + 0];
        feats8[5] = he[h * 4 + 1];
        feats8[6] = he[h * 4 + 2];
        feats8[7] = he[h * 4 + 3];
        kn[((size_t)(b * H_ + h)) * T_ + t] = knorm;
    }
    __syncthreads();
    if (threadIdx.x < 32) {
        float a = b1[threadIdx.x];
        #pragma unroll
        for (int j = 0; j < 8; ++j) a = fmaf(feats8[j], w1[j * 32 + threadIdx.x], a);
        hf1[threadIdx.x] = siluf_(a);
    }
    __syncthreads();
    if (threadIdx.x < 32) {
        float a = b2[threadIdx.x];
        #pragma unroll
        for (int j = 0; j < 32; ++j) a = fmaf(hf1[j], w2[j * 32 + threadIdx.x], a);
        hf[threadIdx.x] = siluf_(a);
    }
    __syncthreads();
    if (threadIdx.x == 0) {
        float bb = bbb[0], bd = bdb[0], lv = lamb[0], ab = abb[0], ad = adb[0];
        #pragma unroll
        for (int j = 0; j < 32; ++j) {
            float hj = hf[j];
            bb = fmaf(hj, bbw[j], bb);
            bd = fmaf(hj, bdw[j], bd);
            lv = fmaf(hj, lamw[j], lv);
            ab = fmaf(hj, abw[j], ab);
            ad = fmaf(hj, adw[j], ad);
        }
        size_t o = ((size_t)(b * H_ + h)) * T_ + t;
        bf[o]  = sigmoidf_(bb + bd);
        bs[o]  = sigmoidf_(bb - bd);
        lm[o]  = sigmoidf_(lv);
        af[o]  = sigmoidf_(ab + ad);
        as2[o] = sigmoidf_(ab - ad);
    }
}

// ------ precompute scan operands: ku[bh][t][k], d[rbh][t][k], scal4 {amp,beta,qkb} --
__global__ __launch_bounds__(128) void precomp_k(
    const float* __restrict__ kc, const float* __restrict__ qc,
    const float* __restrict__ kn,
    const float* __restrict__ af, const float* __restrict__ as2,
    const float* __restrict__ bf, const float* __restrict__ bs,
    const float* __restrict__ gchan,
    float* __restrict__ kuA, float* __restrict__ dA, float4* __restrict__ scal4A)
{
    const int t = blockIdx.x;
    const int y = blockIdx.y;                // rule*32 + b*16 + h
    const int rule = y >> 5, b = (y >> 4) & 1, h = y & 15;
    const int k = threadIdx.x;
    const int sb = (b * 16 + h) * 256 + t;
    const float knv = kn[sb];
    const float am  = (rule ? as2 : af)[sb];
    const float btv = (rule ? bs : bf)[sb];
    const size_t idx = (size_t)(b * 256 + t) * D_ + h * 128 + k;
    const float kuv = kc[idx] / (knv + 1e-6f);
    if (rule == 0) kuA[((size_t)(b * 16 + h) * 256 + t) * 128 + k] = kuv;
    dA[((size_t)y * 256 + t) * 128 + k] = exp2f(gchan[h * 128 + k] * am);
    float p = qc[idx] * kuv;
    #pragma unroll
    for (int o = 32; o > 0; o >>= 1) p += __shfl_xor(p, o);
    __shared__ float pp[2];
    if ((k & 63) == 0) pp[k >> 6] = p;
    __syncthreads();
    if (k == 0) {
        float4 s; s.x = am; s.y = btv; s.z = (pp[0] + pp[1]) * btv; s.w = 0.f;
        scal4A[(size_t)y * 256 + t] = s;
    }
}

// ---------------- delta-rule scan v5: distance-2 prefetch, 2 waves/SIMD ------------
// 2048 waves = 512 blocks x 4. Wave = 16 kl x 4 vg; lane owns S[8k][1v]; 4 v-cols/wave.
// XCD-swizzled: XCD x owns bh [4x,4x+4). No transcendentals in-loop (dA stream).
struct DR5 { float ku[8], q[8], d[8], v; float4 sc; };

__device__ __forceinline__ void dload5(DR5& r,
    const float* __restrict__ pku, const float* __restrict__ pq,
    const float* __restrict__ pd, const float* __restrict__ pv,
    const float4* __restrict__ psc, int t)
{
    float4 a0 = *(const float4*)(pku + (size_t)t * 128);
    float4 a1 = *(const float4*)(pku + (size_t)t * 128 + 4);
    r.ku[0]=a0.x; r.ku[1]=a0.y; r.ku[2]=a0.z; r.ku[3]=a0.w;
    r.ku[4]=a1.x; r.ku[5]=a1.y; r.ku[6]=a1.z; r.ku[7]=a1.w;
    float4 b0 = *(const float4*)(pq + (size_t)t * D_);
    float4 b1 = *(const float4*)(pq + (size_t)t * D_ + 4);
    r.q[0]=b0.x; r.q[1]=b0.y; r.q[2]=b0.z; r.q[3]=b0.w;
    r.q[4]=b1.x; r.q[5]=b1.y; r.q[6]=b1.z; r.q[7]=b1.w;
    float4 c0 = *(const float4*)(pd + (size_t)t * 128);
    float4 c1 = *(const float4*)(pd + (size_t)t * 128 + 4);
    r.d[0]=c0.x; r.d[1]=c0.y; r.d[2]=c0.z; r.d[3]=c0.w;
    r.d[4]=c1.x; r.d[5]=c1.y; r.d[6]=c1.z; r.d[7]=c1.w;
    r.v  = pv[(size_t)t * D_];
    r.sc = psc[t];
}

__global__ __launch_bounds__(256) void delta_wave5(
    const float* __restrict__ qc, const float* __restrict__ vc,
    const float* __restrict__ kuA, const float* __restrict__ dA,
    const float4* __restrict__ scal4A,
    float* __restrict__ o_fast, float* __restrict__ o_slow)
{
    const int p  = blockIdx.x;                    // 0..511 ; XCD = p & 7
    const int lb = (p & 7) * 64 + (p >> 3);       // logical: bh(5) | rule(1) | vg8(3)
    const int bh   = lb >> 4;                     // 0..31 (4 bh per XCD)
    const int rule = (lb >> 3) & 1;
    const int vg8  = lb & 7;
    const int wid  = threadIdx.x >> 6;
    const int lane = threadIdx.x & 63;
    const int kl = lane & 15, vg = lane >> 4;
    const int vchunk = vg8 * 4 + wid;             // 0..31
    const int vcol   = vchunk * 4 + vg;           // 0..127
    const int b = bh >> 4, h = bh & 15;
    const int rbh = rule * 32 + bh;

    const float*  __restrict__ pku = kuA + ((size_t)bh  * 256) * 128 + kl * 8;
    const float*  __restrict__ pd  = dA  + ((size_t)rbh * 256) * 128 + kl * 8;
    const float*  __restrict__ pq  = qc + (size_t)b * T_ * D_ + h * 128 + kl * 8;
    const float*  __restrict__ pv  = vc + (size_t)b * T_ * D_ + h * 128 + vcol;
    const float4* __restrict__ psc = scal4A + (size_t)rbh * 256;
    float* __restrict__ obase = (rule ? o_slow : o_fast)
                                + (size_t)b * T_ * D_ + h * 128 + vcol;

    float S[8];
    #pragma unroll
    for (int j = 0; j < 8; ++j) S[j] = 0.f;

#define DSTEP(TT, CUR) do {                                                        \
    float kud[8], qd[8];                                                           \
    _Pragma("unroll")                                                              \
    for (int j = 0; j < 8; ++j) {                                                  \
        kud[j] = CUR.ku[j] * CUR.d[j];                                             \
        qd[j]  = CUR.q[j]  * CUR.d[j];                                             \
    }                                                                              \
    float vp = 0.f, oq = 0.f;                                                      \
    _Pragma("unroll")                                                              \
    for (int j = 0; j < 8; ++j) {                                                  \
        vp = fmaf(kud[j], S[j], vp);                                               \
        oq = fmaf(qd[j],  S[j], oq);                                               \
    }                                                                              \
    vp += __shfl_xor(vp, 1); oq += __shfl_xor(oq, 1);                              \
    vp += __shfl_xor(vp, 2); oq += __shfl_xor(oq, 2);                              \
    vp += __shfl_xor(vp, 4); oq += __shfl_xor(oq, 4);                              \
    vp += __shfl_xor(vp, 8); oq += __shfl_xor(oq, 8);                              \
    float dv = CUR.v - vp;                                                         \
    float o = fmaf(CUR.sc.z, dv, oq);                                              \
    float btdv = CUR.sc.y * dv;                                                    \
    _Pragma("unroll")                                                              \
    for (int j = 0; j < 8; ++j)                                                    \
        S[j] = fmaf(CUR.d[j], S[j], CUR.ku[j] * btdv);                             \
    if (kl == 0) obase[(size_t)(TT) * D_] = o;                                     \
    if ((TT) + 2 < T_) dload5(CUR, pku, pq, pd, pv, psc, (TT) + 2);                \
} while (0)

    DR5 rA, rB;
    dload5(rA, pku, pq, pd, pv, psc, 0);
    dload5(rB, pku, pq, pd, pv, psc, 1);
    for (int t = 0; t < T_; t += 2) {
        DSTEP(t,     rA);
        DSTEP(t + 1, rB);
    }
#undef DSTEP
}

// ---------------- combine fast/slow + RMSNorm + sigmoid gate -> bf16 ----------------
__global__ __launch_bounds__(128) void combine_k(
    const float* __restrict__ of, const float* __restrict__ os,
    const float* __restrict__ lm, const float* __restrict__ graw,
    const float* __restrict__ g2b, const float* __restrict__ onw,
    ushort_t* __restrict__ ocb)
{
    int blk = blockIdx.x;          // (b*T+t)*H + h
    int h = blk & 15, bt = blk >> 4;
    int b = bt / T_, t = bt % T_;
    int v = threadIdx.x;
    size_t idx = (size_t)bt * D_ + h * 128 + v;
    float l = lm[((size_t)(b * H_ + h)) * T_ + t];
    float o = l * of[idx] + (1.f - l) * os[idx];
    float s = o * o;
    #pragma unroll
    for (int off = 32; off > 0; off >>= 1) s += __shfl_xor(s, off);
    __shared__ float ws2[2];
    if ((threadIdx.x & 63) == 0) ws2[threadIdx.x >> 6] = s;
    __syncthreads();
    float tot = ws2[0] + ws2[1];
    float rms = sqrtf(tot / 128.f + 1e-5f);
    float g = graw[idx] + g2b[h * 128 + v];
    ocb[idx] = f2bf(o / rms * onw[v] * sigmoidf_(g));
}

extern "C" void kernel_launch(void* const* d_in, const int* in_sizes, int n_in,
                              void* d_out, int out_size, void* d_ws, size_t ws_size,
                              hipStream_t stream)
{
    const float* x        = (const float*)d_in[0];
    const float* wq       = (const float*)d_in[1];
    const float* wk       = (const float*)d_in[2];
    const float* wv       = (const float*)d_in[3];
    const float* conv_q_w = (const float*)d_in[4];
    const float* conv_k_w = (const float*)d_in[5];
    const float* conv_v_w = (const float*)d_in[6];
    const float* A_log    = (const float*)d_in[7];
    const float* dt_bias  = (const float*)d_in[8];
    const float* proxy_w  = (const float*)d_in[9];
    const float* unc_w    = (const float*)d_in[10];
    const float* he       = (const float*)d_in[11];
    const float* mlp_w1   = (const float*)d_in[12];
    const float* mlp_b1   = (const float*)d_in[13];
    const float* mlp_w2   = (const float*)d_in[14];
    const float* mlp_b2   = (const float*)d_in[15];
    const float* bb_w     = (const float*)d_in[16];
    const float* bb_b     = (const float*)d_in[17];
    const float* bd_w     = (const float*)d_in[18];
    const float* bd_b     = (const float*)d_in[19];
    const float* lam_w    = (const float*)d_in[20];
    const float* lam_b    = (const float*)d_in[21];
    const float* ab_w     = (const float*)d_in[22];
    const float* ab_b     = (const float*)d_in[23];
    const float* ad_w     = (const float*)d_in[24];
    const float* ad_b     = (const float*)d_in[25];
    const float* g1_w     = (const float*)d_in[26];
    const float* g2_w     = (const float*)d_in[27];
    const float* g2_b     = (const float*)d_in[28];
    const float* onorm_w  = (const float*)d_in[29];
    const float* wo       = (const float*)d_in[30];
    float* out = (float*)d_out;

    float* ws = (float*)d_ws;
    const size_t SZ = (size_t)BT_ * D_;              // 1,048,576
    float* C_big = ws;                               // 512*6336 = 3,244,032
    float* qc    = C_big + (size_t)512 * 6336;
    float* kc    = qc + SZ;
    float* vc    = kc + SZ;
    float* graw  = vc + SZ;
    float* bf    = graw + SZ;                        // 6 x 8192 scalars
    float* bs    = bf + 8192;
    float* lm    = bs + 8192;
    float* af    = lm + 8192;
    float* as2   = af + 8192;
    float* kn    = as2 + 8192;
    float* gchan = kn + 8192;                        // 2048
    float* scal4 = gchan + 2048;                     // 64*256*4 = 65,536
    float* kuA   = scal4 + 65536;                    // 32*256*128 = 1,048,576
    float* dA    = kuA + 1048576;                    // 64*256*128 = 2,097,152
    float* fend  = dA + 2097152;
    ushort_t* xb    = (ushort_t*)fend;               // 1,048,576 bf16
    ushort_t* gtmpb = xb + SZ;                       // 65,536 bf16
    // total ~= 45 MB

    float* o_fast  = C_big;                          // overlay (C_big dead after feats_k)
    float* o_slow  = C_big + SZ;
    ushort_t* ocb  = xb;                             // overlay (xb dead after gemm_proj)
    float* vhatA   = kuA;                            // overlay (kuA written in precomp, after feats_k)
    ushort_t* kcb  = (ushort_t*)dA;                  // overlay (dA written in precomp, after vhat GEMM)

    dim3 blk256(256);
    const float QSCALE = 0.08838834764831845f;       // DK^-0.5

    // 1. x -> bf16
    cvt_bf16<<<dim3(1024), blk256, 0, stream>>>(x, xb, (int)SZ);
    // 2. fused projections: [512][6336] = xb @ [wq|wk|wv|unc|g1]
    gemm_proj<<<dim3(99, 8), blk256, 0, stream>>>(xb, wq, wk, wv, unc_w, g1_w, C_big);
    // 3. gtmp cols -> bf16
    cvt_strided<<<dim3(64), blk256, 0, stream>>>(C_big, gtmpb);
    // 4. graw = gtmpb @ g2_w
    gemm_one<<<dim3(32, 8), blk256, 0, stream>>>(gtmpb, g2_w, graw, 2048, 128);
    // 5. conv + silu (q pre-scaled); kc also emitted as bf16
    conv_fused<<<dim3(24, BT_), blk256, 0, stream>>>(C_big, conv_q_w, conv_k_w, conv_v_w,
                                                     qc, kc, vc, kcb, QSCALE);
    // 6. vhat = kcb[8192,128] @ proxy[128,128]  (MFMA)
    gemm_one<<<dim3(2, 128), blk256, 0, stream>>>(kcb, proxy_w, vhatA, 128, 128);
    // 7. gchan precompute
    gchan_k<<<dim3(8), blk256, 0, stream>>>(A_log, dt_bias, gchan);
    // 8. per-(b,t,h) features + MLP (+entropy inline)
    feats_k<<<dim3(BT_ * H_), dim3(128), 0, stream>>>(
        kc, vc, vhatA, C_big, he, mlp_w1, mlp_b1, mlp_w2, mlp_b2,
        bb_w, bb_b, bd_w, bd_b, lam_w, lam_b, ab_w, ab_b, ad_w, ad_b,
        bf, bs, lm, af, as2, kn);
    // 9. precompute ku / d / packed per-step scalars (overwrites overlays — safe)
    precomp_k<<<dim3(256, 64), dim3(128), 0, stream>>>(
        kc, qc, kn, af, as2, bf, bs, gchan, kuA, dA, (float4*)scal4);
    // 10. delta-rule scan (2048 waves = 2/SIMD, XCD-swizzled, dist-2 prefetch)
    delta_wave5<<<dim3(512), blk256, 0, stream>>>(qc, vc, kuA, dA,
                                                  (const float4*)scal4,
                                                  o_fast, o_slow);
    // 11. combine + rmsnorm + gate -> bf16
    combine_k<<<dim3(BT_ * H_), dim3(128), 0, stream>>>(o_fast, o_slow, lm, graw,
                                                        g2_b, onorm_w, ocb);
    // 12. output projection
    gemm_one<<<dim3(32, 8), blk256, 0, stream>>>(ocb, wo, out, 2048, 2048);
}

// Round 9
// 303.313 us; speedup vs baseline: 1.0439x; 1.0439x over previous
//
#include <hip/hip_runtime.h>
#include <hip/hip_bf16.h>
#include <math.h>

#define H_ 16
#define DK_ 128
#define DV_ 128
#define D_ 2048
#define T_ 256
#define B_ 2
#define BT_ 512

typedef __attribute__((ext_vector_type(8))) short short8v;
typedef __attribute__((ext_vector_type(4))) float float4v;
typedef unsigned short ushort_t;

__device__ __forceinline__ float sigmoidf_(float x){ return 1.f/(1.f+expf(-x)); }
__device__ __forceinline__ float siluf_(float x){ return x/(1.f+expf(-x)); }
__device__ __forceinline__ ushort_t f2bf(float f){
    __hip_bfloat16 h = __float2bfloat16(f);
    return *reinterpret_cast<ushort_t*>(&h);
}
// swizzled LDS index (shorts) for 64-row x 32-col bf16 tiles; k multiple of 8 in use
__device__ __forceinline__ int swz(int row, int k){
    return row * 32 + ((((k >> 3) ^ (row & 3)) << 3) | (k & 7));
}

// ---------------- fp32 -> bf16 elementwise ----------------
__global__ void cvt_bf16(const float* __restrict__ in, ushort_t* __restrict__ out, int n){
    int i = (blockIdx.x * 256 + threadIdx.x) * 4;
    if (i >= n) return;
    float4 v = *(const float4*)&in[i];
    union { ushort_t s[4]; unsigned long long u; } p;
    p.s[0] = f2bf(v.x); p.s[1] = f2bf(v.y); p.s[2] = f2bf(v.z); p.s[3] = f2bf(v.w);
    *(unsigned long long*)&out[i] = p.u;
}

// ---------------- strided cvt: C_big cols [6208,6336) -> gtmpb [512][128] bf16 ------
__global__ void cvt_strided(const float* __restrict__ Cb, ushort_t* __restrict__ out){
    int i = (blockIdx.x * 256 + threadIdx.x) * 4;   // 65536 total
    int m = i >> 7, c = i & 127;
    float4 v = *(const float4*)&Cb[(size_t)m * 6336 + 6208 + c];
    union { ushort_t s[4]; unsigned long long u; } p;
    p.s[0] = f2bf(v.x); p.s[1] = f2bf(v.y); p.s[2] = f2bf(v.z); p.s[3] = f2bf(v.w);
    *(unsigned long long*)&out[i] = p.u;
}

// ---------------- GEMM core: C[64x64 tile] = A_bf16[M,K] @ W_f32[K,Nst] -------------
__device__ __forceinline__ void gemm_core(
    const ushort_t* __restrict__ A, int K,
    const float* __restrict__ W, int Nst, int nloc0,
    float* __restrict__ C, int Cst, int m0, int n0out)
{
    __shared__ ushort_t Asub[2048];
    __shared__ ushort_t Bsub[2048];
    const int tid = threadIdx.x;
    const int wid = tid >> 6, lane = tid & 63;
    const int wr = (wid >> 1) * 32, wc = (wid & 1) * 32;
    const int lr = lane & 15, lk = (lane >> 4) * 8;
    const int rowA = tid >> 2, kqA = tid & 3;       // A staging: b128 per thread
    const int nW = tid & 63, kqW = tid >> 6;        // W staging: 8 scalar rows

    float4v acc[2][2];
    #pragma unroll
    for (int i = 0; i < 2; ++i)
        #pragma unroll
        for (int j = 0; j < 2; ++j) acc[i][j] = (float4v){0.f, 0.f, 0.f, 0.f};

    short8v aRa, aRb;
    float wRa[8], wRb[8];

#define LOADT(AR, WR, KOFF) do {                                                   \
    AR = *(const short8v*)&A[(size_t)(m0 + rowA) * K + (KOFF) + kqA * 8];          \
    _Pragma("unroll")                                                              \
    for (int r = 0; r < 8; ++r)                                                    \
        WR[r] = W[(size_t)((KOFF) + kqW * 8 + r) * Nst + nloc0 + nW];              \
} while (0)
#define STORET(AR, WR) do {                                                        \
    *(short8v*)&Asub[swz(rowA, kqA * 8)] = AR;                                     \
    union { ushort_t s[8]; short8v v; } pk;                                        \
    _Pragma("unroll")                                                              \
    for (int r = 0; r < 8; ++r) pk.s[r] = f2bf(WR[r]);                             \
    *(short8v*)&Bsub[swz(nW, kqW * 8)] = pk.v;                                     \
} while (0)
#define FRAGMMA() do {                                                             \
    short8v af0 = *(const short8v*)&Asub[swz(wr + lr, lk)];                        \
    short8v af1 = *(const short8v*)&Asub[swz(wr + 16 + lr, lk)];                   \
    short8v bf0 = *(const short8v*)&Bsub[swz(wc + lr, lk)];                        \
    short8v bf1 = *(const short8v*)&Bsub[swz(wc + 16 + lr, lk)];                   \
    acc[0][0] = __builtin_amdgcn_mfma_f32_16x16x32_bf16(af0, bf0, acc[0][0],0,0,0);\
    acc[0][1] = __builtin_amdgcn_mfma_f32_16x16x32_bf16(af0, bf1, acc[0][1],0,0,0);\
    acc[1][0] = __builtin_amdgcn_mfma_f32_16x16x32_bf16(af1, bf0, acc[1][0],0,0,0);\
    acc[1][1] = __builtin_amdgcn_mfma_f32_16x16x32_bf16(af1, bf1, acc[1][1],0,0,0);\
} while (0)

    LOADT(aRa, wRa, 0);
    for (int k0 = 0; k0 < K; k0 += 64) {
        STORET(aRa, wRa);
        __syncthreads();
        if (k0 + 32 < K) LOADT(aRb, wRb, k0 + 32);
        FRAGMMA();
        __syncthreads();
        STORET(aRb, wRb);
        __syncthreads();
        if (k0 + 64 < K) LOADT(aRa, wRa, k0 + 64);
        FRAGMMA();
        __syncthreads();
    }
#undef LOADT
#undef STORET
#undef FRAGMMA
    const int lq = (lane >> 4) * 4;
    #pragma unroll
    for (int mi = 0; mi < 2; ++mi)
        #pragma unroll
        for (int ni = 0; ni < 2; ++ni)
            #pragma unroll
            for (int j = 0; j < 4; ++j)
                C[(size_t)(m0 + wr + mi * 16 + lq + j) * Cst + (n0out + wc + ni * 16 + lr)]
                    = acc[mi][ni][j];
}

// fused projection GEMM: N = 6336 = wq(2048) | wk(2048) | wv(2048) | unc(64) | g1(128)
__global__ __launch_bounds__(256) void gemm_proj(const ushort_t* __restrict__ A,
    const float* __restrict__ wq, const float* __restrict__ wk, const float* __restrict__ wv,
    const float* __restrict__ unc, const float* __restrict__ g1, float* __restrict__ C)
{
    int n0 = blockIdx.x * 64, m0 = blockIdx.y * 64;
    const float* W; int nloc, Nst;
    if (n0 < 2048)      { W = wq;  nloc = n0;        Nst = 2048; }
    else if (n0 < 4096) { W = wk;  nloc = n0 - 2048; Nst = 2048; }
    else if (n0 < 6144) { W = wv;  nloc = n0 - 4096; Nst = 2048; }
    else if (n0 < 6208) { W = unc; nloc = n0 - 6144; Nst = 64; }
    else                { W = g1;  nloc = n0 - 6208; Nst = 128; }
    gemm_core(A, 2048, W, Nst, nloc, C, 6336, m0, n0);
}

// single-weight GEMM: C[M,N] = A[M,K] @ W[K,N]
__global__ __launch_bounds__(256) void gemm_one(const ushort_t* __restrict__ A,
    const float* __restrict__ W, float* __restrict__ C, int N, int K)
{
    gemm_core(A, K, W, N, blockIdx.x * 64, C, N, blockIdx.y * 64, blockIdx.x * 64);
}

// ---------------- fused causal depthwise conv (K=4) + SiLU over q|k|v --------------
__global__ void conv_fused(const float* __restrict__ Cb,
    const float* __restrict__ wq, const float* __restrict__ wk, const float* __restrict__ wv,
    float* __restrict__ qc, float* __restrict__ kc, float* __restrict__ vc,
    ushort_t* __restrict__ kcb, float qscale)
{
    int c  = blockIdx.x * 256 + threadIdx.x;   // 0..6143
    int bt = blockIdx.y;
    int b  = bt / T_, t = bt % T_;
    int which = c >> 11, cloc = c & 2047;
    const float* w = which == 0 ? wq : which == 1 ? wk : wv;
    float* o = which == 0 ? qc : which == 1 ? kc : vc;
    float scale = which == 0 ? qscale : 1.f;
    float acc = 0.f;
    #pragma unroll
    for (int j = 0; j < 4; ++j) {
        int tt = t - 3 + j;
        if (tt >= 0) acc = fmaf(w[cloc * 4 + j], Cb[((size_t)(b * T_ + tt)) * 6336 + c], acc);
    }
    float r = siluf_(acc) * scale;
    o[(size_t)bt * D_ + cloc] = r;
    if (which == 1) kcb[(size_t)bt * D_ + cloc] = f2bf(r);
}

// ---------------- g_chan (pre-scaled by log2(e) for exp2f) ----------------
__global__ void gchan_k(const float* __restrict__ A_log, const float* __restrict__ dt_bias,
                        float* __restrict__ gchan)
{
    int i = blockIdx.x * 256 + threadIdx.x;
    int h = i >> 7;
    float x = dt_bias[i];
    float sp = (x > 20.f) ? x : log1pf(expf(x));
    gchan[i] = -expf(A_log[h]) * sp * 1.44269504088896f;
}

// ---------------- per-(b,t,h) features (+inline entropy) + tiny MLP ----------------
__global__ __launch_bounds__(128) void feats_k(
    const float* __restrict__ kc, const float* __restrict__ vc,
    const float* __restrict__ vhatA, const float* __restrict__ Cb,
    const float* __restrict__ he,
    const float* __restrict__ w1, const float* __restrict__ b1,
    const float* __restrict__ w2, const float* __restrict__ b2,
    const float* __restrict__ bbw, const float* __restrict__ bbb,
    const float* __restrict__ bdw, const float* __restrict__ bdb,
    const float* __restrict__ lamw, const float* __restrict__ lamb,
    const float* __restrict__ abw, const float* __restrict__ abb,
    const float* __restrict__ adw, const float* __restrict__ adb,
    float* __restrict__ bf, float* __restrict__ bs, float* __restrict__ lm,
    float* __restrict__ af, float* __restrict__ as2, float* __restrict__ kn)
{
    int blk = blockIdx.x;          // (b*T+t)*H + h
    int h = blk & 15, bt = blk >> 4;
    int b = bt / T_, t = bt % T_;
    int v = threadIdx.x;           // 0..127
    __shared__ float part[2][5];
    __shared__ float tot5[5];
    __shared__ float feats8[8];
    __shared__ float hf1[32];
    __shared__ float hf[32];
    __shared__ float entSh;

    if (v < 64) {
        float x = Cb[(size_t)bt * 6336 + 6144 + v];
        float m = x;
        #pragma unroll
        for (int o = 32; o > 0; o >>= 1) m = fmaxf(m, __shfl_xor(m, o));
        float e = expf(x - m);
        float s = e;
        #pragma unroll
        for (int o = 32; o > 0; o >>= 1) s += __shfl_xor(s, o);
        float lp = (x - m) - logf(s);
        float c = -expf(lp) * lp;
        #pragma unroll
        for (int o = 32; o > 0; o >>= 1) c += __shfl_xor(c, o);
        if (v == 0) entSh = c / logf(64.f);
    }

    size_t base = (size_t)bt * D_ + h * 128;
    float kval = kc[base + v];
    float vval = vc[base + v];
    float vhat = vhatA[(size_t)blk * 128 + v];

    float e = vval - vhat;
    float sums[5] = {kval * kval, vval * vval, vhat * vhat, vval * vhat, e * e};
    #pragma unroll
    for (int i = 0; i < 5; ++i) {
        float s = sums[i];
        #pragma unroll
        for (int o = 32; o > 0; o >>= 1) s += __shfl_xor(s, o);
        if ((threadIdx.x & 63) == 0) part[threadIdx.x >> 6][i] = s;
    }
    __syncthreads();
    if (threadIdx.x < 5) tot5[threadIdx.x] = part[0][threadIdx.x] + part[1][threadIdx.x];
    __syncthreads();
    if (threadIdx.x == 0) {
        float k2 = tot5[0], v2 = tot5[1], vh2 = tot5[2], vvh = tot5[3], e2 = tot5[4];
        float knorm = sqrtf(k2);
        float err_n = sqrtf(e2);
        float v_n = sqrtf(v2);
        float vh_n = sqrtf(vh2);
        feats8[0] = entSh;
        feats8[1] = err_n / (v_n + 1e-6f);
        feats8[2] = vvh / (v_n * vh_n + 1e-6f);
        feats8[3] = log1pf(err_n);
        feats8[4] = he[h * 4 + 0];
        feats8[5] = he[h * 4 + 1];
        feats8[6] = he[h * 4 + 2];
        feats8[7] = he[h * 4 + 3];
        kn[((size_t)(b * H_ + h)) * T_ + t] = knorm;
    }
    __syncthreads();
    if (threadIdx.x < 32) {
        float a = b1[threadIdx.x];
        #pragma unroll
        for (int j = 0; j < 8; ++j) a = fmaf(feats8[j], w1[j * 32 + threadIdx.x], a);
        hf1[threadIdx.x] = siluf_(a);
    }
    __syncthreads();
    if (threadIdx.x < 32) {
        float a = b2[threadIdx.x];
        #pragma unroll
        for (int j = 0; j < 32; ++j) a = fmaf(hf1[j], w2[j * 32 + threadIdx.x], a);
        hf[threadIdx.x] = siluf_(a);
    }
    __syncthreads();
    if (threadIdx.x == 0) {
        float bb = bbb[0], bd = bdb[0], lv = lamb[0], ab = abb[0], ad = adb[0];
        #pragma unroll
        for (int j = 0; j < 32; ++j) {
            float hj = hf[j];
            bb = fmaf(hj, bbw[j], bb);
            bd = fmaf(hj, bdw[j], bd);
            lv = fmaf(hj, lamw[j], lv);
            ab = fmaf(hj, abw[j], ab);
            ad = fmaf(hj, adw[j], ad);
        }
        size_t o = ((size_t)(b * H_ + h)) * T_ + t;
        bf[o]  = sigmoidf_(bb + bd);
        bs[o]  = sigmoidf_(bb - bd);
        lm[o]  = sigmoidf_(lv);
        af[o]  = sigmoidf_(ab + ad);
        as2[o] = sigmoidf_(ab - ad);
    }
}

// ------ precompute scan operands: ku[bh][t][k], scal4 {amp,beta,qkb} ----------------
__global__ __launch_bounds__(128) void precomp_k(
    const float* __restrict__ kc, const float* __restrict__ qc,
    const float* __restrict__ kn,
    const float* __restrict__ af, const float* __restrict__ as2,
    const float* __restrict__ bf, const float* __restrict__ bs,
    float* __restrict__ kuA, float4* __restrict__ scal4A)
{
    const int t = blockIdx.x;
    const int y = blockIdx.y;                // rule*32 + b*16 + h
    const int rule = y >> 5, b = (y >> 4) & 1, h = y & 15;
    const int k = threadIdx.x;
    const int sb = (b * 16 + h) * 256 + t;
    const float knv = kn[sb];
    const float am  = (rule ? as2 : af)[sb];
    const float btv = (rule ? bs : bf)[sb];
    const size_t idx = (size_t)(b * 256 + t) * D_ + h * 128 + k;
    const float kuv = kc[idx] / (knv + 1e-6f);
    if (rule == 0) kuA[((size_t)(b * 16 + h) * 256 + t) * 128 + k] = kuv;
    float p = qc[idx] * kuv;
    #pragma unroll
    for (int o = 32; o > 0; o >>= 1) p += __shfl_xor(p, o);
    __shared__ float pp[2];
    if ((k & 63) == 0) pp[k >> 6] = p;
    __syncthreads();
    if (k == 0) {
        float4 s; s.x = am; s.y = btv; s.z = (pp[0] + pp[1]) * btv; s.w = 0.f;
        scal4A[(size_t)y * 256 + t] = s;
    }
}

// ---------------- delta-rule scan v6b: LDS-chunked operands, 256 blocks ------------
// Block = (rule, bh, v-quarter): 4 waves cover 32 v-cols; lane owns S[8k][2v].
// 16-step chunks of {ku,q,v,sc} staged in double-buffered LDS; 1 barrier / 16 steps.
// Bank-swizzled k-rows: f(g) = g*8 + (g>>2)*4, max word 139 -> row width 144.
__global__ __launch_bounds__(256) void delta_wave6(
    const float* __restrict__ qc, const float* __restrict__ vc,
    const float* __restrict__ kuA, const float4* __restrict__ scal4A,
    const float* __restrict__ gchan,
    float* __restrict__ o_fast, float* __restrict__ o_slow)
{
    const int p  = blockIdx.x;                    // 0..255 ; XCD = p & 7
    const int lb = (p & 7) * 32 + (p >> 3);       // bh*8 + rule*4 + vq
    const int bh = lb >> 3, rule = (lb >> 2) & 1, vq = lb & 3;
    const int b = bh >> 4, h = bh & 15;
    const int rbh = rule * 32 + bh;
    const int tid = threadIdx.x;
    const int wid = tid >> 6, lane = tid & 63;
    const int kl = lane & 15, vg = lane >> 4;
    const int vloc = wid * 8 + vg * 2;            // 0..30 within 32-col slice
    const int vcol = vq * 32 + vloc;

    __shared__ float kuL[2][16][144];
    __shared__ float qL [2][16][144];
    __shared__ float vL [2][16][32];
    __shared__ float scL[2][16][4];

    const float*  __restrict__ pkuG = kuA + (size_t)bh * 256 * 128;
    const float*  __restrict__ pqG  = qc + (size_t)b * T_ * D_ + h * 128;
    const float*  __restrict__ pvG  = vc + (size_t)b * T_ * D_ + h * 128 + vq * 32;
    const float4* __restrict__ pscG = scal4A + (size_t)rbh * 256;
    float* __restrict__ obase = (rule ? o_slow : o_fast)
                                + (size_t)b * T_ * D_ + h * 128 + vcol;

    // staging roles: threads<128 stage ku+v; threads>=128 stage q (+sc for first 16)
    const int srow = (tid & 127) >> 3;            // 0..15
    const int scol = (tid & 7) * 16;              // 0..112
    const bool isK = tid < 128;
    const int ck0 = scol >> 3;                    // 8-float group index (even)
    const int fo_w0 = ck0 * 8 + (ck0 >> 2) * 4;
    const int fo_w1 = (ck0 + 1) * 8 + ((ck0 + 1) >> 2) * 4;

    float4 sb0, sb1, sb2, sb3, svb, ssc;

    float gch[8];
    #pragma unroll
    for (int j = 0; j < 8; ++j) gch[j] = gchan[h * 128 + kl * 8 + j];

    float S[8][2];
    #pragma unroll
    for (int j = 0; j < 8; ++j) { S[j][0] = 0.f; S[j][1] = 0.f; }

#define STAGE_LOAD(C) do {                                                         \
    const int t0_ = (C) * 16;                                                      \
    if (isK) {                                                                     \
        const float* src = pkuG + (size_t)(t0_ + srow) * 128 + scol;               \
        sb0 = *(const float4*)(src);      sb1 = *(const float4*)(src + 4);         \
        sb2 = *(const float4*)(src + 8);  sb3 = *(const float4*)(src + 12);        \
        svb = *(const float4*)(pvG + (size_t)(t0_ + srow) * D_ + (tid & 7) * 4);   \
    } else {                                                                       \
        const float* src = pqG + (size_t)(t0_ + srow) * D_ + scol;                 \
        sb0 = *(const float4*)(src);      sb1 = *(const float4*)(src + 4);         \
        sb2 = *(const float4*)(src + 8);  sb3 = *(const float4*)(src + 12);        \
        if ((tid & 127) < 16) ssc = *(const float4*)&pscG[t0_ + (tid & 127)];      \
    }                                                                              \
} while (0)

#define STAGE_WRITE(BI) do {                                                       \
    if (isK) {                                                                     \
        *(float4*)&kuL[BI][srow][fo_w0]     = sb0;                                 \
        *(float4*)&kuL[BI][srow][fo_w0 + 4] = sb1;                                 \
        *(float4*)&kuL[BI][srow][fo_w1]     = sb2;                                 \
        *(float4*)&kuL[BI][srow][fo_w1 + 4] = sb3;                                 \
        *(float4*)&vL[BI][srow][(tid & 7) * 4] = svb;                              \
    } else {                                                                       \
        *(float4*)&qL[BI][srow][fo_w0]     = sb0;                                  \
        *(float4*)&qL[BI][srow][fo_w0 + 4] = sb1;                                  \
        *(float4*)&qL[BI][srow][fo_w1]     = sb2;                                  \
        *(float4*)&qL[BI][srow][fo_w1 + 4] = sb3;                                  \
        if ((tid & 127) < 16) *(float4*)&scL[BI][tid & 127][0] = ssc;              \
    }                                                                              \
} while (0)

    const int fo = kl * 8 + (kl >> 2) * 4;

    STAGE_LOAD(0);
    STAGE_WRITE(0);
    __syncthreads();

    for (int c = 0; c < 16; ++c) {
        if (c < 15) STAGE_LOAD(c + 1);
        const int bi = c & 1;
        const int tb = c * 16;
        #pragma unroll
        for (int ts = 0; ts < 16; ++ts) {
            float4 a0 = *(const float4*)&kuL[bi][ts][fo];
            float4 a1 = *(const float4*)&kuL[bi][ts][fo + 4];
            float4 q0 = *(const float4*)&qL[bi][ts][fo];
            float4 q1 = *(const float4*)&qL[bi][ts][fo + 4];
            float2 vv = *(const float2*)&vL[bi][ts][vloc];
            float4 sc = *(const float4*)&scL[bi][ts][0];
            float ku[8] = {a0.x, a0.y, a0.z, a0.w, a1.x, a1.y, a1.z, a1.w};
            float qv[8] = {q0.x, q0.y, q0.z, q0.w, q1.x, q1.y, q1.z, q1.w};
            float d[8];
            #pragma unroll
            for (int j = 0; j < 8; ++j) d[j] = exp2f(gch[j] * sc.x);
            float vp0 = 0.f, vp1 = 0.f, oq0 = 0.f, oq1 = 0.f;
            #pragma unroll
            for (int j = 0; j < 8; ++j) {
                float kud = ku[j] * d[j], qd = qv[j] * d[j];
                vp0 = fmaf(kud, S[j][0], vp0);
                vp1 = fmaf(kud, S[j][1], vp1);
                oq0 = fmaf(qd,  S[j][0], oq0);
                oq1 = fmaf(qd,  S[j][1], oq1);
            }
            vp0 += __shfl_xor(vp0, 1); vp1 += __shfl_xor(vp1, 1);
            oq0 += __shfl_xor(oq0, 1); oq1 += __shfl_xor(oq1, 1);
            vp0 += __shfl_xor(vp0, 2); vp1 += __shfl_xor(vp1, 2);
            oq0 += __shfl_xor(oq0, 2); oq1 += __shfl_xor(oq1, 2);
            vp0 += __shfl_xor(vp0, 4); vp1 += __shfl_xor(vp1, 4);
            oq0 += __shfl_xor(oq0, 4); oq1 += __shfl_xor(oq1, 4);
            vp0 += __shfl_xor(vp0, 8); vp1 += __shfl_xor(vp1, 8);
            oq0 += __shfl_xor(oq0, 8); oq1 += __shfl_xor(oq1, 8);
            float dv0 = vv.x - vp0, dv1 = vv.y - vp1;
            float o0 = fmaf(sc.z, dv0, oq0);
            float o1 = fmaf(sc.z, dv1, oq1);
            float bd0 = sc.y * dv0, bd1 = sc.y * dv1;
            #pragma unroll
            for (int j = 0; j < 8; ++j) {
                S[j][0] = fmaf(d[j], S[j][0], ku[j] * bd0);
                S[j][1] = fmaf(d[j], S[j][1], ku[j] * bd1);
            }
            if (kl == 0) {
                float2 ov; ov.x = o0; ov.y = o1;
                *(float2*)&obase[(size_t)(tb + ts) * D_] = ov;
            }
        }
        if (c < 15) STAGE_WRITE((c + 1) & 1);
        __syncthreads();
    }
#undef STAGE_LOAD
#undef STAGE_WRITE
}

// ---------------- combine fast/slow + RMSNorm + sigmoid gate -> bf16 ----------------
__global__ __launch_bounds__(128) void combine_k(
    const float* __restrict__ of, const float* __restrict__ os,
    const float* __restrict__ lm, const float* __restrict__ graw,
    const float* __restrict__ g2b, const float* __restrict__ onw,
    ushort_t* __restrict__ ocb)
{
    int blk = blockIdx.x;          // (b*T+t)*H + h
    int h = blk & 15, bt = blk >> 4;
    int b = bt / T_, t = bt % T_;
    int v = threadIdx.x;
    size_t idx = (size_t)bt * D_ + h * 128 + v;
    float l = lm[((size_t)(b * H_ + h)) * T_ + t];
    float o = l * of[idx] + (1.f - l) * os[idx];
    float s = o * o;
    #pragma unroll
    for (int off = 32; off > 0; off >>= 1) s += __shfl_xor(s, off);
    __shared__ float ws2[2];
    if ((threadIdx.x & 63) == 0) ws2[threadIdx.x >> 6] = s;
    __syncthreads();
    float tot = ws2[0] + ws2[1];
    float rms = sqrtf(tot / 128.f + 1e-5f);
    float g = graw[idx] + g2b[h * 128 + v];
    ocb[idx] = f2bf(o / rms * onw[v] * sigmoidf_(g));
}

extern "C" void kernel_launch(void* const* d_in, const int* in_sizes, int n_in,
                              void* d_out, int out_size, void* d_ws, size_t ws_size,
                              hipStream_t stream)
{
    const float* x        = (const float*)d_in[0];
    const float* wq       = (const float*)d_in[1];
    const float* wk       = (const float*)d_in[2];
    const float* wv       = (const float*)d_in[3];
    const float* conv_q_w = (const float*)d_in[4];
    const float* conv_k_w = (const float*)d_in[5];
    const float* conv_v_w = (const float*)d_in[6];
    const float* A_log    = (const float*)d_in[7];
    const float* dt_bias  = (const float*)d_in[8];
    const float* proxy_w  = (const float*)d_in[9];
    const float* unc_w    = (const float*)d_in[10];
    const float* he       = (const float*)d_in[11];
    const float* mlp_w1   = (const float*)d_in[12];
    const float* mlp_b1   = (const float*)d_in[13];
    const float* mlp_w2   = (const float*)d_in[14];
    const float* mlp_b2   = (const float*)d_in[15];
    const float* bb_w     = (const float*)d_in[16];
    const float* bb_b     = (const float*)d_in[17];
    const float* bd_w     = (const float*)d_in[18];
    const float* bd_b     = (const float*)d_in[19];
    const float* lam_w    = (const float*)d_in[20];
    const float* lam_b    = (const float*)d_in[21];
    const float* ab_w     = (const float*)d_in[22];
    const float* ab_b     = (const float*)d_in[23];
    const float* ad_w     = (const float*)d_in[24];
    const float* ad_b     = (const float*)d_in[25];
    const float* g1_w     = (const float*)d_in[26];
    const float* g2_w     = (const float*)d_in[27];
    const float* g2_b     = (const float*)d_in[28];
    const float* onorm_w  = (const float*)d_in[29];
    const float* wo       = (const float*)d_in[30];
    float* out = (float*)d_out;

    float* ws = (float*)d_ws;
    const size_t SZ = (size_t)BT_ * D_;              // 1,048,576
    float* C_big = ws;                               // 512*6336 = 3,244,032
    float* qc    = C_big + (size_t)512 * 6336;
    float* kc    = qc + SZ;
    float* vc    = kc + SZ;
    float* graw  = vc + SZ;
    float* bf    = graw + SZ;                        // 6 x 8192 scalars
    float* bs    = bf + 8192;
    float* lm    = bs + 8192;
    float* af    = lm + 8192;
    float* as2   = af + 8192;
    float* kn    = as2 + 8192;
    float* gchan = kn + 8192;                        // 2048
    float* scal4 = gchan + 2048;                     // 64*256*4 = 65,536
    float* kuA   = scal4 + 65536;                    // 32*256*128 = 1,048,576
    float* scr2  = kuA + 1048576;                    // 524,288 floats (kcb bf16)
    float* fend  = scr2 + 524288;
    ushort_t* xb    = (ushort_t*)fend;               // 1,048,576 bf16
    ushort_t* gtmpb = xb + SZ;                       // 65,536 bf16

    float* o_fast  = C_big;                          // overlay (C_big dead after feats_k)
    float* o_slow  = C_big + SZ;
    ushort_t* ocb  = xb;                             // overlay (xb dead after gemm_proj)
    float* vhatA   = kuA;                            // overlay (kuA written in precomp, after feats_k)
    ushort_t* kcb  = (ushort_t*)scr2;

    dim3 blk256(256);
    const float QSCALE = 0.08838834764831845f;       // DK^-0.5

    // 1. x -> bf16
    cvt_bf16<<<dim3(1024), blk256, 0, stream>>>(x, xb, (int)SZ);
    // 2. fused projections: [512][6336] = xb @ [wq|wk|wv|unc|g1]
    gemm_proj<<<dim3(99, 8), blk256, 0, stream>>>(xb, wq, wk, wv, unc_w, g1_w, C_big);
    // 3. gtmp cols -> bf16
    cvt_strided<<<dim3(64), blk256, 0, stream>>>(C_big, gtmpb);
    // 4. graw = gtmpb @ g2_w
    gemm_one<<<dim3(32, 8), blk256, 0, stream>>>(gtmpb, g2_w, graw, 2048, 128);
    // 5. conv + silu (q pre-scaled); kc also emitted as bf16
    conv_fused<<<dim3(24, BT_), blk256, 0, stream>>>(C_big, conv_q_w, conv_k_w, conv_v_w,
                                                     qc, kc, vc, kcb, QSCALE);
    // 6. vhat = kcb[8192,128] @ proxy[128,128]  (MFMA)
    gemm_one<<<dim3(2, 128), blk256, 0, stream>>>(kcb, proxy_w, vhatA, 128, 128);
    // 7. gchan precompute
    gchan_k<<<dim3(8), blk256, 0, stream>>>(A_log, dt_bias, gchan);
    // 8. per-(b,t,h) features + MLP (+entropy inline)
    feats_k<<<dim3(BT_ * H_), dim3(128), 0, stream>>>(
        kc, vc, vhatA, C_big, he, mlp_w1, mlp_b1, mlp_w2, mlp_b2,
        bb_w, bb_b, bd_w, bd_b, lam_w, lam_b, ab_w, ab_b, ad_w, ad_b,
        bf, bs, lm, af, as2, kn);
    // 9. precompute ku + packed per-step scalars (overwrites vhatA overlay — safe)
    precomp_k<<<dim3(256, 64), dim3(128), 0, stream>>>(
        kc, qc, kn, af, as2, bf, bs, kuA, (float4*)scal4);
    // 10. delta-rule scan: LDS-chunked operands, 256 blocks, 1 barrier / 16 steps
    delta_wave6<<<dim3(256), blk256, 0, stream>>>(qc, vc, kuA, (const float4*)scal4,
                                                  gchan, o_fast, o_slow);
    // 11. combine + rmsnorm + gate -> bf16
    combine_k<<<dim3(BT_ * H_), dim3(128), 0, stream>>>(o_fast, o_slow, lm, graw,
                                                        g2_b, onorm_w, ocb);
    // 12. output projection
    gemm_one<<<dim3(32, 8), blk256, 0, stream>>>(ocb, wo, out, 2048, 2048);
}

// Round 10
// 272.171 us; speedup vs baseline: 1.1633x; 1.1144x over previous
//
#include <hip/hip_runtime.h>
#include <hip/hip_bf16.h>
#include <math.h>

#define H_ 16
#define DK_ 128
#define DV_ 128
#define D_ 2048
#define T_ 256
#define B_ 2
#define BT_ 512

typedef __attribute__((ext_vector_type(8))) short short8v;
typedef __attribute__((ext_vector_type(4))) float float4v;
typedef unsigned short ushort_t;

__device__ __forceinline__ float sigmoidf_(float x){ return 1.f/(1.f+expf(-x)); }
__device__ __forceinline__ float siluf_(float x){ return x/(1.f+expf(-x)); }
__device__ __forceinline__ ushort_t f2bf(float f){
    __hip_bfloat16 h = __float2bfloat16(f);
    return *reinterpret_cast<ushort_t*>(&h);
}
// swizzled LDS index (shorts) for 64-row x 32-col bf16 tiles; k multiple of 8 in use
__device__ __forceinline__ int swz(int row, int k){
    return row * 32 + ((((k >> 3) ^ (row & 3)) << 3) | (k & 7));
}

// DPP row-rotation sum over a 16-lane row (pure VALU, no LDS pipe).
// ROW_ROR:N = dpp_ctrl 0x120+N; rotations by 1,2,4,8 give every lane the row total.
template<int CTRL>
__device__ __forceinline__ float ror_add_(float x){
    return x + __int_as_float(__builtin_amdgcn_update_dpp(
        0, __float_as_int(x), CTRL, 0xF, 0xF, true));
}
__device__ __forceinline__ float rsum16_(float x){
    x = ror_add_<0x121>(x);
    x = ror_add_<0x122>(x);
    x = ror_add_<0x124>(x);
    x = ror_add_<0x128>(x);
    return x;
}

// ---------------- fp32 -> bf16 elementwise ----------------
__global__ void cvt_bf16(const float* __restrict__ in, ushort_t* __restrict__ out, int n){
    int i = (blockIdx.x * 256 + threadIdx.x) * 4;
    if (i >= n) return;
    float4 v = *(const float4*)&in[i];
    union { ushort_t s[4]; unsigned long long u; } p;
    p.s[0] = f2bf(v.x); p.s[1] = f2bf(v.y); p.s[2] = f2bf(v.z); p.s[3] = f2bf(v.w);
    *(unsigned long long*)&out[i] = p.u;
}

// ---------------- strided cvt: C_big cols [6208,6336) -> gtmpb [512][128] bf16 ------
__global__ void cvt_strided(const float* __restrict__ Cb, ushort_t* __restrict__ out){
    int i = (blockIdx.x * 256 + threadIdx.x) * 4;   // 65536 total
    int m = i >> 7, c = i & 127;
    float4 v = *(const float4*)&Cb[(size_t)m * 6336 + 6208 + c];
    union { ushort_t s[4]; unsigned long long u; } p;
    p.s[0] = f2bf(v.x); p.s[1] = f2bf(v.y); p.s[2] = f2bf(v.z); p.s[3] = f2bf(v.w);
    *(unsigned long long*)&out[i] = p.u;
}

// ---------------- GEMM core: C[64x64 tile] = A_bf16[M,K] @ W_f32[K,Nst] -------------
__device__ __forceinline__ void gemm_core(
    const ushort_t* __restrict__ A, int K,
    const float* __restrict__ W, int Nst, int nloc0,
    float* __restrict__ C, int Cst, int m0, int n0out)
{
    __shared__ ushort_t Asub[2048];
    __shared__ ushort_t Bsub[2048];
    const int tid = threadIdx.x;
    const int wid = tid >> 6, lane = tid & 63;
    const int wr = (wid >> 1) * 32, wc = (wid & 1) * 32;
    const int lr = lane & 15, lk = (lane >> 4) * 8;
    const int rowA = tid >> 2, kqA = tid & 3;       // A staging: b128 per thread
    const int nW = tid & 63, kqW = tid >> 6;        // W staging: 8 scalar rows

    float4v acc[2][2];
    #pragma unroll
    for (int i = 0; i < 2; ++i)
        #pragma unroll
        for (int j = 0; j < 2; ++j) acc[i][j] = (float4v){0.f, 0.f, 0.f, 0.f};

    short8v aRa, aRb;
    float wRa[8], wRb[8];

#define LOADT(AR, WR, KOFF) do {                                                   \
    AR = *(const short8v*)&A[(size_t)(m0 + rowA) * K + (KOFF) + kqA * 8];          \
    _Pragma("unroll")                                                              \
    for (int r = 0; r < 8; ++r)                                                    \
        WR[r] = W[(size_t)((KOFF) + kqW * 8 + r) * Nst + nloc0 + nW];              \
} while (0)
#define STORET(AR, WR) do {                                                        \
    *(short8v*)&Asub[swz(rowA, kqA * 8)] = AR;                                     \
    union { ushort_t s[8]; short8v v; } pk;                                        \
    _Pragma("unroll")                                                              \
    for (int r = 0; r < 8; ++r) pk.s[r] = f2bf(WR[r]);                             \
    *(short8v*)&Bsub[swz(nW, kqW * 8)] = pk.v;                                     \
} while (0)
#define FRAGMMA() do {                                                             \
    short8v af0 = *(const short8v*)&Asub[swz(wr + lr, lk)];                        \
    short8v af1 = *(const short8v*)&Asub[swz(wr + 16 + lr, lk)];                   \
    short8v bf0 = *(const short8v*)&Bsub[swz(wc + lr, lk)];                        \
    short8v bf1 = *(const short8v*)&Bsub[swz(wc + 16 + lr, lk)];                   \
    acc[0][0] = __builtin_amdgcn_mfma_f32_16x16x32_bf16(af0, bf0, acc[0][0],0,0,0);\
    acc[0][1] = __builtin_amdgcn_mfma_f32_16x16x32_bf16(af0, bf1, acc[0][1],0,0,0);\
    acc[1][0] = __builtin_amdgcn_mfma_f32_16x16x32_bf16(af1, bf0, acc[1][0],0,0,0);\
    acc[1][1] = __builtin_amdgcn_mfma_f32_16x16x32_bf16(af1, bf1, acc[1][1],0,0,0);\
} while (0)

    LOADT(aRa, wRa, 0);
    for (int k0 = 0; k0 < K; k0 += 64) {
        STORET(aRa, wRa);
        __syncthreads();
        if (k0 + 32 < K) LOADT(aRb, wRb, k0 + 32);
        FRAGMMA();
        __syncthreads();
        STORET(aRb, wRb);
        __syncthreads();
        if (k0 + 64 < K) LOADT(aRa, wRa, k0 + 64);
        FRAGMMA();
        __syncthreads();
    }
#undef LOADT
#undef STORET
#undef FRAGMMA
    const int lq = (lane >> 4) * 4;
    #pragma unroll
    for (int mi = 0; mi < 2; ++mi)
        #pragma unroll
        for (int ni = 0; ni < 2; ++ni)
            #pragma unroll
            for (int j = 0; j < 4; ++j)
                C[(size_t)(m0 + wr + mi * 16 + lq + j) * Cst + (n0out + wc + ni * 16 + lr)]
                    = acc[mi][ni][j];
}

// fused projection GEMM: N = 6336 = wq(2048) | wk(2048) | wv(2048) | unc(64) | g1(128)
__global__ __launch_bounds__(256) void gemm_proj(const ushort_t* __restrict__ A,
    const float* __restrict__ wq, const float* __restrict__ wk, const float* __restrict__ wv,
    const float* __restrict__ unc, const float* __restrict__ g1, float* __restrict__ C)
{
    int n0 = blockIdx.x * 64, m0 = blockIdx.y * 64;
    const float* W; int nloc, Nst;
    if (n0 < 2048)      { W = wq;  nloc = n0;        Nst = 2048; }
    else if (n0 < 4096) { W = wk;  nloc = n0 - 2048; Nst = 2048; }
    else if (n0 < 6144) { W = wv;  nloc = n0 - 4096; Nst = 2048; }
    else if (n0 < 6208) { W = unc; nloc = n0 - 6144; Nst = 64; }
    else                { W = g1;  nloc = n0 - 6208; Nst = 128; }
    gemm_core(A, 2048, W, Nst, nloc, C, 6336, m0, n0);
}

// single-weight GEMM: C[M,N] = A[M,K] @ W[K,N]
__global__ __launch_bounds__(256) void gemm_one(const ushort_t* __restrict__ A,
    const float* __restrict__ W, float* __restrict__ C, int N, int K)
{
    gemm_core(A, K, W, N, blockIdx.x * 64, C, N, blockIdx.y * 64, blockIdx.x * 64);
}

// ---------------- fused causal depthwise conv (K=4) + SiLU over q|k|v --------------
__global__ void conv_fused(const float* __restrict__ Cb,
    const float* __restrict__ wq, const float* __restrict__ wk, const float* __restrict__ wv,
    float* __restrict__ qc, float* __restrict__ kc, float* __restrict__ vc,
    ushort_t* __restrict__ kcb, float qscale)
{
    int c  = blockIdx.x * 256 + threadIdx.x;   // 0..6143
    int bt = blockIdx.y;
    int b  = bt / T_, t = bt % T_;
    int which = c >> 11, cloc = c & 2047;
    const float* w = which == 0 ? wq : which == 1 ? wk : wv;
    float* o = which == 0 ? qc : which == 1 ? kc : vc;
    float scale = which == 0 ? qscale : 1.f;
    float acc = 0.f;
    #pragma unroll
    for (int j = 0; j < 4; ++j) {
        int tt = t - 3 + j;
        if (tt >= 0) acc = fmaf(w[cloc * 4 + j], Cb[((size_t)(b * T_ + tt)) * 6336 + c], acc);
    }
    float r = siluf_(acc) * scale;
    o[(size_t)bt * D_ + cloc] = r;
    if (which == 1) kcb[(size_t)bt * D_ + cloc] = f2bf(r);
}

// ---------------- g_chan (pre-scaled by log2(e) for exp2f) ----------------
__global__ void gchan_k(const float* __restrict__ A_log, const float* __restrict__ dt_bias,
                        float* __restrict__ gchan)
{
    int i = blockIdx.x * 256 + threadIdx.x;
    int h = i >> 7;
    float x = dt_bias[i];
    float sp = (x > 20.f) ? x : log1pf(expf(x));
    gchan[i] = -expf(A_log[h]) * sp * 1.44269504088896f;
}

// ---------------- per-(b,t,h) features (+inline entropy) + tiny MLP ----------------
__global__ __launch_bounds__(128) void feats_k(
    const float* __restrict__ kc, const float* __restrict__ vc,
    const float* __restrict__ vhatA, const float* __restrict__ Cb,
    const float* __restrict__ he,
    const float* __restrict__ w1, const float* __restrict__ b1,
    const float* __restrict__ w2, const float* __restrict__ b2,
    const float* __restrict__ bbw, const float* __restrict__ bbb,
    const float* __restrict__ bdw, const float* __restrict__ bdb,
    const float* __restrict__ lamw, const float* __restrict__ lamb,
    const float* __restrict__ abw, const float* __restrict__ abb,
    const float* __restrict__ adw, const float* __restrict__ adb,
    float* __restrict__ bf, float* __restrict__ bs, float* __restrict__ lm,
    float* __restrict__ af, float* __restrict__ as2, float* __restrict__ kn)
{
    int blk = blockIdx.x;          // (b*T+t)*H + h
    int h = blk & 15, bt = blk >> 4;
    int b = bt / T_, t = bt % T_;
    int v = threadIdx.x;           // 0..127
    __shared__ float part[2][5];
    __shared__ float tot5[5];
    __shared__ float feats8[8];
    __shared__ float hf1[32];
    __shared__ float hf[32];
    __shared__ float entSh;

    if (v < 64) {
        float x = Cb[(size_t)bt * 6336 + 6144 + v];
        float m = x;
        #pragma unroll
        for (int o = 32; o > 0; o >>= 1) m = fmaxf(m, __shfl_xor(m, o));
        float e = expf(x - m);
        float s = e;
        #pragma unroll
        for (int o = 32; o > 0; o >>= 1) s += __shfl_xor(s, o);
        float lp = (x - m) - logf(s);
        float c = -expf(lp) * lp;
        #pragma unroll
        for (int o = 32; o > 0; o >>= 1) c += __shfl_xor(c, o);
        if (v == 0) entSh = c / logf(64.f);
    }

    size_t base = (size_t)bt * D_ + h * 128;
    float kval = kc[base + v];
    float vval = vc[base + v];
    float vhat = vhatA[(size_t)blk * 128 + v];

    float e = vval - vhat;
    float sums[5] = {kval * kval, vval * vval, vhat * vhat, vval * vhat, e * e};
    #pragma unroll
    for (int i = 0; i < 5; ++i) {
        float s = sums[i];
        #pragma unroll
        for (int o = 32; o > 0; o >>= 1) s += __shfl_xor(s, o);
        if ((threadIdx.x & 63) == 0) part[threadIdx.x >> 6][i] = s;
    }
    __syncthreads();
    if (threadIdx.x < 5) tot5[threadIdx.x] = part[0][threadIdx.x] + part[1][threadIdx.x];
    __syncthreads();
    if (threadIdx.x == 0) {
        float k2 = tot5[0], v2 = tot5[1], vh2 = tot5[2], vvh = tot5[3], e2 = tot5[4];
        float knorm = sqrtf(k2);
        float err_n = sqrtf(e2);
        float v_n = sqrtf(v2);
        float vh_n = sqrtf(vh2);
        feats8[0] = entSh;
        feats8[1] = err_n / (v_n + 1e-6f);
        feats8[2] = vvh / (v_n * vh_n + 1e-6f);
        feats8[3] = log1pf(err_n);
        feats8[4] = he[h * 4 + 0];
        feats8[5] = he[h * 4 + 1];
        feats8[6] = he[h * 4 + 2];
        feats8[7] = he[h * 4 + 3];
        kn[((size_t)(b * H_ + h)) * T_ + t] = knorm;
    }
    __syncthreads();
    if (threadIdx.x < 32) {
        float a = b1[threadIdx.x];
        #pragma unroll
        for (int j = 0; j < 8; ++j) a = fmaf(feats8[j], w1[j * 32 + threadIdx.x], a);
        hf1[threadIdx.x] = siluf_(a);
    }
    __syncthreads();
    if (threadIdx.x < 32) {
        float a = b2[threadIdx.x];
        #pragma unroll
        for (int j = 0; j < 32; ++j) a = fmaf(hf1[j], w2[j * 32 + threadIdx.x], a);
        hf[threadIdx.x] = siluf_(a);
    }
    __syncthreads();
    if (threadIdx.x == 0) {
        float bb = bbb[0], bd = bdb[0], lv = lamb[0], ab = abb[0], ad = adb[0];
        #pragma unroll
        for (int j = 0; j < 32; ++j) {
            float hj = hf[j];
            bb = fmaf(hj, bbw[j], bb);
            bd = fmaf(hj, bdw[j], bd);
            lv = fmaf(hj, lamw[j], lv);
            ab = fmaf(hj, abw[j], ab);
            ad = fmaf(hj, adw[j], ad);
        }
        size_t o = ((size_t)(b * H_ + h)) * T_ + t;
        bf[o]  = sigmoidf_(bb + bd);
        bs[o]  = sigmoidf_(bb - bd);
        lm[o]  = sigmoidf_(lv);
        af[o]  = sigmoidf_(ab + ad);
        as2[o] = sigmoidf_(ab - ad);
    }
}

// ------ precompute scan operands: ku[bh][t][k], scal4 {amp,beta,qkb} ----------------
__global__ __launch_bounds__(128) void precomp_k(
    const float* __restrict__ kc, const float* __restrict__ qc,
    const float* __restrict__ kn,
    const float* __restrict__ af, const float* __restrict__ as2,
    const float* __restrict__ bf, const float* __restrict__ bs,
    float* __restrict__ kuA, float4* __restrict__ scal4A)
{
    const int t = blockIdx.x;
    const int y = blockIdx.y;                // rule*32 + b*16 + h
    const int rule = y >> 5, b = (y >> 4) & 1, h = y & 15;
    const int k = threadIdx.x;
    const int sb = (b * 16 + h) * 256 + t;
    const float knv = kn[sb];
    const float am  = (rule ? as2 : af)[sb];
    const float btv = (rule ? bs : bf)[sb];
    const size_t idx = (size_t)(b * 256 + t) * D_ + h * 128 + k;
    const float kuv = kc[idx] / (knv + 1e-6f);
    if (rule == 0) kuA[((size_t)(b * 16 + h) * 256 + t) * 128 + k] = kuv;
    float p = qc[idx] * kuv;
    #pragma unroll
    for (int o = 32; o > 0; o >>= 1) p += __shfl_xor(p, o);
    __shared__ float pp[2];
    if ((k & 63) == 0) pp[k >> 6] = p;
    __syncthreads();
    if (k == 0) {
        float4 s; s.x = am; s.y = btv; s.z = (pp[0] + pp[1]) * btv; s.w = 0.f;
        scal4A[(size_t)y * 256 + t] = s;
    }
}

// ---------------- delta-rule scan v7: DPP row-rotation reductions ------------------
// Same structure as v6b (passed r9): 256 blocks = (rule,bh,vq); 4 waves / 32 v-cols;
// lane owns S[8k][2v]; 16-step LDS chunks, 1 barrier/16 steps. Reduction now pure
// VALU DPP (row_ror 1/2/4/8) instead of ds_swizzle — removes ~480cyc/step LDS latency.
__global__ __launch_bounds__(256) void delta_wave6(
    const float* __restrict__ qc, const float* __restrict__ vc,
    const float* __restrict__ kuA, const float4* __restrict__ scal4A,
    const float* __restrict__ gchan,
    float* __restrict__ o_fast, float* __restrict__ o_slow)
{
    const int p  = blockIdx.x;                    // 0..255 ; XCD = p & 7
    const int lb = (p & 7) * 32 + (p >> 3);       // bh*8 + rule*4 + vq
    const int bh = lb >> 3, rule = (lb >> 2) & 1, vq = lb & 3;
    const int b = bh >> 4, h = bh & 15;
    const int rbh = rule * 32 + bh;
    const int tid = threadIdx.x;
    const int wid = tid >> 6, lane = tid & 63;
    const int kl = lane & 15, vg = lane >> 4;
    const int vloc = wid * 8 + vg * 2;            // 0..30 within 32-col slice
    const int vcol = vq * 32 + vloc;

    __shared__ float kuL[2][16][144];
    __shared__ float qL [2][16][144];
    __shared__ float vL [2][16][32];
    __shared__ float scL[2][16][4];

    const float*  __restrict__ pkuG = kuA + (size_t)bh * 256 * 128;
    const float*  __restrict__ pqG  = qc + (size_t)b * T_ * D_ + h * 128;
    const float*  __restrict__ pvG  = vc + (size_t)b * T_ * D_ + h * 128 + vq * 32;
    const float4* __restrict__ pscG = scal4A + (size_t)rbh * 256;
    float* __restrict__ obase = (rule ? o_slow : o_fast)
                                + (size_t)b * T_ * D_ + h * 128 + vcol;

    // staging roles: threads<128 stage ku+v; threads>=128 stage q (+sc for first 16)
    const int srow = (tid & 127) >> 3;            // 0..15
    const int scol = (tid & 7) * 16;              // 0..112
    const bool isK = tid < 128;
    const int ck0 = scol >> 3;                    // 8-float group index (even)
    const int fo_w0 = ck0 * 8 + (ck0 >> 2) * 4;
    const int fo_w1 = (ck0 + 1) * 8 + ((ck0 + 1) >> 2) * 4;

    float4 sb0, sb1, sb2, sb3, svb, ssc;

    float gch[8];
    #pragma unroll
    for (int j = 0; j < 8; ++j) gch[j] = gchan[h * 128 + kl * 8 + j];

    float S[8][2];
    #pragma unroll
    for (int j = 0; j < 8; ++j) { S[j][0] = 0.f; S[j][1] = 0.f; }

#define STAGE_LOAD(C) do {                                                         \
    const int t0_ = (C) * 16;                                                      \
    if (isK) {                                                                     \
        const float* src = pkuG + (size_t)(t0_ + srow) * 128 + scol;               \
        sb0 = *(const float4*)(src);      sb1 = *(const float4*)(src + 4);         \
        sb2 = *(const float4*)(src + 8);  sb3 = *(const float4*)(src + 12);        \
        svb = *(const float4*)(pvG + (size_t)(t0_ + srow) * D_ + (tid & 7) * 4);   \
    } else {                                                                       \
        const float* src = pqG + (size_t)(t0_ + srow) * D_ + scol;                 \
        sb0 = *(const float4*)(src);      sb1 = *(const float4*)(src + 4);         \
        sb2 = *(const float4*)(src + 8);  sb3 = *(const float4*)(src + 12);        \
        if ((tid & 127) < 16) ssc = *(const float4*)&pscG[t0_ + (tid & 127)];      \
    }                                                                              \
} while (0)

#define STAGE_WRITE(BI) do {                                                       \
    if (isK) {                                                                     \
        *(float4*)&kuL[BI][srow][fo_w0]     = sb0;                                 \
        *(float4*)&kuL[BI][srow][fo_w0 + 4] = sb1;                                 \
        *(float4*)&kuL[BI][srow][fo_w1]     = sb2;                                 \
        *(float4*)&kuL[BI][srow][fo_w1 + 4] = sb3;                                 \
        *(float4*)&vL[BI][srow][(tid & 7) * 4] = svb;                              \
    } else {                                                                       \
        *(float4*)&qL[BI][srow][fo_w0]     = sb0;                                  \
        *(float4*)&qL[BI][srow][fo_w0 + 4] = sb1;                                  \
        *(float4*)&qL[BI][srow][fo_w1]     = sb2;                                  \
        *(float4*)&qL[BI][srow][fo_w1 + 4] = sb3;                                  \
        if ((tid & 127) < 16) *(float4*)&scL[BI][tid & 127][0] = ssc;              \
    }                                                                              \
} while (0)

    const int fo = kl * 8 + (kl >> 2) * 4;

    STAGE_LOAD(0);
    STAGE_WRITE(0);
    __syncthreads();

    for (int c = 0; c < 16; ++c) {
        if (c < 15) STAGE_LOAD(c + 1);
        const int bi = c & 1;
        const int tb = c * 16;
        #pragma unroll
        for (int ts = 0; ts < 16; ++ts) {
            float4 a0 = *(const float4*)&kuL[bi][ts][fo];
            float4 a1 = *(const float4*)&kuL[bi][ts][fo + 4];
            float4 q0 = *(const float4*)&qL[bi][ts][fo];
            float4 q1 = *(const float4*)&qL[bi][ts][fo + 4];
            float2 vv = *(const float2*)&vL[bi][ts][vloc];
            float4 sc = *(const float4*)&scL[bi][ts][0];
            float ku[8] = {a0.x, a0.y, a0.z, a0.w, a1.x, a1.y, a1.z, a1.w};
            float qv[8] = {q0.x, q0.y, q0.z, q0.w, q1.x, q1.y, q1.z, q1.w};
            float d[8];
            #pragma unroll
            for (int j = 0; j < 8; ++j) d[j] = exp2f(gch[j] * sc.x);
            // split dot chains (2x4) to halve dependent-fma latency
            float vp0a = 0.f, vp0b = 0.f, vp1a = 0.f, vp1b = 0.f;
            float oq0a = 0.f, oq0b = 0.f, oq1a = 0.f, oq1b = 0.f;
            #pragma unroll
            for (int j = 0; j < 4; ++j) {
                float kudA = ku[j] * d[j],     qdA = qv[j] * d[j];
                float kudB = ku[j+4] * d[j+4], qdB = qv[j+4] * d[j+4];
                vp0a = fmaf(kudA, S[j][0], vp0a);   vp0b = fmaf(kudB, S[j+4][0], vp0b);
                vp1a = fmaf(kudA, S[j][1], vp1a);   vp1b = fmaf(kudB, S[j+4][1], vp1b);
                oq0a = fmaf(qdA,  S[j][0], oq0a);   oq0b = fmaf(qdB,  S[j+4][0], oq0b);
                oq1a = fmaf(qdA,  S[j][1], oq1a);   oq1b = fmaf(qdB,  S[j+4][1], oq1b);
            }
            float vp0 = rsum16_(vp0a + vp0b);
            float vp1 = rsum16_(vp1a + vp1b);
            float oq0 = rsum16_(oq0a + oq0b);
            float oq1 = rsum16_(oq1a + oq1b);
            float dv0 = vv.x - vp0, dv1 = vv.y - vp1;
            float o0 = fmaf(sc.z, dv0, oq0);
            float o1 = fmaf(sc.z, dv1, oq1);
            float bd0 = sc.y * dv0, bd1 = sc.y * dv1;
            #pragma unroll
            for (int j = 0; j < 8; ++j) {
                S[j][0] = fmaf(d[j], S[j][0], ku[j] * bd0);
                S[j][1] = fmaf(d[j], S[j][1], ku[j] * bd1);
            }
            if (kl == 0) {
                float2 ov; ov.x = o0; ov.y = o1;
                *(float2*)&obase[(size_t)(tb + ts) * D_] = ov;
            }
        }
        if (c < 15) STAGE_WRITE((c + 1) & 1);
        __syncthreads();
    }
#undef STAGE_LOAD
#undef STAGE_WRITE
}

// ---------------- combine fast/slow + RMSNorm + sigmoid gate -> bf16 ----------------
__global__ __launch_bounds__(128) void combine_k(
    const float* __restrict__ of, const float* __restrict__ os,
    const float* __restrict__ lm, const float* __restrict__ graw,
    const float* __restrict__ g2b, const float* __restrict__ onw,
    ushort_t* __restrict__ ocb)
{
    int blk = blockIdx.x;          // (b*T+t)*H + h
    int h = blk & 15, bt = blk >> 4;
    int b = bt / T_, t = bt % T_;
    int v = threadIdx.x;
    size_t idx = (size_t)bt * D_ + h * 128 + v;
    float l = lm[((size_t)(b * H_ + h)) * T_ + t];
    float o = l * of[idx] + (1.f - l) * os[idx];
    float s = o * o;
    #pragma unroll
    for (int off = 32; off > 0; off >>= 1) s += __shfl_xor(s, off);
    __shared__ float ws2[2];
    if ((threadIdx.x & 63) == 0) ws2[threadIdx.x >> 6] = s;
    __syncthreads();
    float tot = ws2[0] + ws2[1];
    float rms = sqrtf(tot / 128.f + 1e-5f);
    float g = graw[idx] + g2b[h * 128 + v];
    ocb[idx] = f2bf(o / rms * onw[v] * sigmoidf_(g));
}

extern "C" void kernel_launch(void* const* d_in, const int* in_sizes, int n_in,
                              void* d_out, int out_size, void* d_ws, size_t ws_size,
                              hipStream_t stream)
{
    const float* x        = (const float*)d_in[0];
    const float* wq       = (const float*)d_in[1];
    const float* wk       = (const float*)d_in[2];
    const float* wv       = (const float*)d_in[3];
    const float* conv_q_w = (const float*)d_in[4];
    const float* conv_k_w = (const float*)d_in[5];
    const float* conv_v_w = (const float*)d_in[6];
    const float* A_log    = (const float*)d_in[7];
    const float* dt_bias  = (const float*)d_in[8];
    const float* proxy_w  = (const float*)d_in[9];
    const float* unc_w    = (const float*)d_in[10];
    const float* he       = (const float*)d_in[11];
    const float* mlp_w1   = (const float*)d_in[12];
    const float* mlp_b1   = (const float*)d_in[13];
    const float* mlp_w2   = (const float*)d_in[14];
    const float* mlp_b2   = (const float*)d_in[15];
    const float* bb_w     = (const float*)d_in[16];
    const float* bb_b     = (const float*)d_in[17];
    const float* bd_w     = (const float*)d_in[18];
    const float* bd_b     = (const float*)d_in[19];
    const float* lam_w    = (const float*)d_in[20];
    const float* lam_b    = (const float*)d_in[21];
    const float* ab_w     = (const float*)d_in[22];
    const float* ab_b     = (const float*)d_in[23];
    const float* ad_w     = (const float*)d_in[24];
    const float* ad_b     = (const float*)d_in[25];
    const float* g1_w     = (const float*)d_in[26];
    const float* g2_w     = (const float*)d_in[27];
    const float* g2_b     = (const float*)d_in[28];
    const float* onorm_w  = (const float*)d_in[29];
    const float* wo       = (const float*)d_in[30];
    float* out = (float*)d_out;

    float* ws = (float*)d_ws;
    const size_t SZ = (size_t)BT_ * D_;              // 1,048,576
    float* C_big = ws;                               // 512*6336 = 3,244,032
    float* qc    = C_big + (size_t)512 * 6336;
    float* kc    = qc + SZ;
    float* vc    = kc + SZ;
    float* graw  = vc + SZ;
    float* bf    = graw + SZ;                        // 6 x 8192 scalars
    float* bs    = bf + 8192;
    float* lm    = bs + 8192;
    float* af    = lm + 8192;
    float* as2   = af + 8192;
    float* kn    = as2 + 8192;
    float* gchan = kn + 8192;                        // 2048
    float* scal4 = gchan + 2048;                     // 64*256*4 = 65,536
    float* kuA   = scal4 + 65536;                    // 32*256*128 = 1,048,576
    float* scr2  = kuA + 1048576;                    // 524,288 floats (kcb bf16)
    float* fend  = scr2 + 524288;
    ushort_t* xb    = (ushort_t*)fend;               // 1,048,576 bf16
    ushort_t* gtmpb = xb + SZ;                       // 65,536 bf16

    float* o_fast  = C_big;                          // overlay (C_big dead after feats_k)
    float* o_slow  = C_big + SZ;
    ushort_t* ocb  = xb;                             // overlay (xb dead after gemm_proj)
    float* vhatA   = kuA;                            // overlay (kuA written in precomp, after feats_k)
    ushort_t* kcb  = (ushort_t*)scr2;

    dim3 blk256(256);
    const float QSCALE = 0.08838834764831845f;       // DK^-0.5

    // 1. x -> bf16
    cvt_bf16<<<dim3(1024), blk256, 0, stream>>>(x, xb, (int)SZ);
    // 2. fused projections: [512][6336] = xb @ [wq|wk|wv|unc|g1]
    gemm_proj<<<dim3(99, 8), blk256, 0, stream>>>(xb, wq, wk, wv, unc_w, g1_w, C_big);
    // 3. gtmp cols -> bf16
    cvt_strided<<<dim3(64), blk256, 0, stream>>>(C_big, gtmpb);
    // 4. graw = gtmpb @ g2_w
    gemm_one<<<dim3(32, 8), blk256, 0, stream>>>(gtmpb, g2_w, graw, 2048, 128);
    // 5. conv + silu (q pre-scaled); kc also emitted as bf16
    conv_fused<<<dim3(24, BT_), blk256, 0, stream>>>(C_big, conv_q_w, conv_k_w, conv_v_w,
                                                     qc, kc, vc, kcb, QSCALE);
    // 6. vhat = kcb[8192,128] @ proxy[128,128]  (MFMA)
    gemm_one<<<dim3(2, 128), blk256, 0, stream>>>(kcb, proxy_w, vhatA, 128, 128);
    // 7. gchan precompute
    gchan_k<<<dim3(8), blk256, 0, stream>>>(A_log, dt_bias, gchan);
    // 8. per-(b,t,h) features + MLP (+entropy inline)
    feats_k<<<dim3(BT_ * H_), dim3(128), 0, stream>>>(
        kc, vc, vhatA, C_big, he, mlp_w1, mlp_b1, mlp_w2, mlp_b2,
        bb_w, bb_b, bd_w, bd_b, lam_w, lam_b, ab_w, ab_b, ad_w, ad_b,
        bf, bs, lm, af, as2, kn);
    // 9. precompute ku + packed per-step scalars (overwrites vhatA overlay — safe)
    precomp_k<<<dim3(256, 64), dim3(128), 0, stream>>>(
        kc, qc, kn, af, as2, bf, bs, kuA, (float4*)scal4);
    // 10. delta-rule scan: DPP reductions, LDS-chunked operands
    delta_wave6<<<dim3(256), blk256, 0, stream>>>(qc, vc, kuA, (const float4*)scal4,
                                                  gchan, o_fast, o_slow);
    // 11. combine + rmsnorm + gate -> bf16
    combine_k<<<dim3(BT_ * H_), dim3(128), 0, stream>>>(o_fast, o_slow, lm, graw,
                                                        g2_b, onorm_w, ocb);
    // 12. output projection
    gemm_one<<<dim3(32, 8), blk256, 0, stream>>>(ocb, wo, out, 2048, 2048);
}